// Round 2
// baseline (817.178 us; speedup 1.0000x reference)
//
#include <hip/hip_runtime.h>
#include <hip/hip_bf16.h>
#include <math.h>

// Problem constants (SoftDotAttention): B=128, S=1024, D=1024.
#define BB 128
#define SS 1024
#define DD 1024
#define NC 8            // number of S-chunks for the fused attention pass
#define SC (SS / NC)    // 128 rows per chunk

// Workspace layout (floats)
#define OFF_TARGET 0
#define OFF_SCORES (BB * DD)                         // 131072
#define OFF_M      (OFF_SCORES + BB * SS)            // 262144
#define OFF_L      (OFF_M + BB * NC)                 // 263168
#define OFF_WCP    (OFF_L + BB * NC)                 // 264192
#define OFF_WC     (OFF_WCP + BB * NC * DD)          // 1312768
#define OFF_FLAG   (OFF_WC + BB * DD)                // 1443840
// total ≈ 5.5 MB << ws_size

// ---------------------------------------------------------------------------
// K0: detect mask element width (1-byte bool vs int32 0/1) from data.
// int32 0/1 little-endian => bytes at offsets 1,2,3 (mod 4) are all zero and
// offset-0 bytes are 0/1 over the first 1024 bytes. A random ~50%-ones bool
// array violates this with probability 1 - 2^-768. Deterministic per input,
// graph-capture safe (no host readback).
// ---------------------------------------------------------------------------
__global__ void detect_mask(const unsigned char* __restrict__ mask,
                            int* __restrict__ flag)
{
    if (threadIdx.x == 0) {
        int isInt32 = 1;
        for (int i = 0; i < 256; ++i) {
            unsigned char b0 = mask[4 * i + 0];
            unsigned char b1 = mask[4 * i + 1];
            unsigned char b2 = mask[4 * i + 2];
            unsigned char b3 = mask[4 * i + 3];
            if (b1 | b2 | b3) { isInt32 = 0; break; }
            if (b0 > 1)       { isInt32 = 0; break; }
        }
        *flag = isInt32;
    }
}

// ---------------------------------------------------------------------------
// K1/K4: C[M,N] = A[M,K] * Bmat[N,K]^T   (both operands K-major, fp32)
// A is h (lda=1024) or concat([wc, h]) (two 1024-wide halves, K=2048).
// Optional tanh epilogue. BM=16, BN=32, KC=64, 256 threads.
// ---------------------------------------------------------------------------
__global__ __launch_bounds__(256) void gemm_nt(
    const float* __restrict__ A0, const float* __restrict__ A1,
    const float* __restrict__ Bm, float* __restrict__ Cout,
    int M, int N, int K, int applyTanh)
{
    __shared__ float As[16][64];
    __shared__ float Bs[32][65];   // pad 65: bank = (c + k) % 32, conflict-free

    const int tid  = threadIdx.x;
    const int bn0  = blockIdx.x * 32;
    const int bm0  = blockIdx.y * 16;
    const int r    = tid >> 5;        // 0..7  (computes rows r and r+8)
    const int ccol = tid & 31;        // 0..31

    const int ar = tid >> 4;          // 0..15   A-load row
    const int ak = (tid & 15) << 2;   // 0,4,...,60

    float acc0 = 0.f, acc1 = 0.f;

    for (int k0 = 0; k0 < K; k0 += 64) {
        // ---- stage A tile (16x64) ----
        const float* Asrc = A0;
        int kk = k0;
        if (A1 != nullptr && k0 >= 1024) { Asrc = A1; kk = k0 - 1024; }
        float4 av = *(const float4*)(Asrc + (size_t)(bm0 + ar) * 1024 + kk + ak);
        *(float4*)&As[ar][ak] = av;

        // ---- stage B tile (32x64) ----
        #pragma unroll
        for (int u = 0; u < 2; ++u) {
            int idx4 = tid + u * 256;          // 0..511
            int c    = idx4 >> 4;              // 0..31
            int k    = (idx4 & 15) << 2;       // 0..60
            float4 bv = *(const float4*)(Bm + (size_t)(bn0 + c) * K + k0 + k);
            Bs[c][k + 0] = bv.x;
            Bs[c][k + 1] = bv.y;
            Bs[c][k + 2] = bv.z;
            Bs[c][k + 3] = bv.w;
        }
        __syncthreads();

        #pragma unroll
        for (int k = 0; k < 64; ++k) {
            float bv = Bs[ccol][k];
            acc0 = fmaf(As[r][k],     bv, acc0);
            acc1 = fmaf(As[r + 8][k], bv, acc1);
        }
        __syncthreads();
    }

    const int col = bn0 + ccol;
    float v0 = applyTanh ? tanhf(acc0) : acc0;
    float v1 = applyTanh ? tanhf(acc1) : acc1;
    Cout[(size_t)(bm0 + r) * N + col]     = v0;
    Cout[(size_t)(bm0 + r + 8) * N + col] = v1;
}

// ---------------------------------------------------------------------------
// K2: fused scores + online softmax partials + partial weighted-context.
// grid = (NC, B), 256 threads = 4 waves. Wave w handles rows s0+w, step 4.
// One context row (1024 f32) == 64 lanes x 4 float4 — loaded once, used for
// both the score dot and the p*ctx accumulation.
// ---------------------------------------------------------------------------
__global__ __launch_bounds__(256) void attn_pass(
    const float* __restrict__ ctx, const float* __restrict__ tgt,
    const unsigned char* __restrict__ mask_u8,
    const int* __restrict__ mask_flag,
    float* __restrict__ scores, float* __restrict__ m_part,
    float* __restrict__ l_part, float* __restrict__ wc_part)
{
    const int b    = blockIdx.y;
    const int ch   = blockIdx.x;
    const int tid  = threadIdx.x;
    const int w    = tid >> 6;
    const int lane = tid & 63;
    const int s0   = ch * SC;

    const int mflag = *mask_flag;   // uniform; L2-cached broadcast
    const int* mask_i32 = (const int*)mask_u8;

    // target fragment: lane covers d = j*256 + lane*4 .. +4
    float4 t4[4];
    const float4* tp = (const float4*)(tgt + (size_t)b * DD);
    #pragma unroll
    for (int j = 0; j < 4; ++j) t4[j] = tp[j * 64 + lane];

    float m = -INFINITY, l = 0.f;
    float4 acc[4];
    #pragma unroll
    for (int j = 0; j < 4; ++j) acc[j] = make_float4(0.f, 0.f, 0.f, 0.f);

    float* srow = scores + (size_t)b * SS;

    for (int i = 0; i < SC / 4; ++i) {
        const int s = s0 + w + i * 4;
        const float4* row = (const float4*)(ctx + ((size_t)b * SS + s) * DD);
        float4 c4[4];
        #pragma unroll
        for (int j = 0; j < 4; ++j) c4[j] = row[j * 64 + lane];

        float part = 0.f;
        #pragma unroll
        for (int j = 0; j < 4; ++j) {
            part = fmaf(c4[j].x, t4[j].x, part);
            part = fmaf(c4[j].y, t4[j].y, part);
            part = fmaf(c4[j].z, t4[j].z, part);
            part = fmaf(c4[j].w, t4[j].w, part);
        }
        #pragma unroll
        for (int off = 32; off >= 1; off >>= 1)
            part += __shfl_xor(part, off, 64);

        const int mraw = mflag ? mask_i32[(size_t)b * SS + s]
                               : (int)mask_u8[(size_t)b * SS + s];
        const bool mk = (mraw != 0);
        const float sc = mk ? -INFINITY : part;
        if (lane == 0) srow[s] = sc;

        if (sc > m) {           // new max (wave-uniform branch)
            const float f = __expf(m - sc);
            l *= f;
            #pragma unroll
            for (int j = 0; j < 4; ++j) {
                acc[j].x *= f; acc[j].y *= f; acc[j].z *= f; acc[j].w *= f;
            }
            m = sc;
        }
        const float p = mk ? 0.f : __expf(sc - m);
        l += p;
        #pragma unroll
        for (int j = 0; j < 4; ++j) {
            acc[j].x = fmaf(p, c4[j].x, acc[j].x);
            acc[j].y = fmaf(p, c4[j].y, acc[j].y);
            acc[j].z = fmaf(p, c4[j].z, acc[j].z);
            acc[j].w = fmaf(p, c4[j].w, acc[j].w);
        }
    }

    // ---- combine the 4 waves ----
    __shared__ float sm[4], sl[4];
    __shared__ float sacc[4][DD];
    if (lane == 0) { sm[w] = m; sl[w] = l; }
    #pragma unroll
    for (int j = 0; j < 4; ++j)
        *(float4*)&sacc[w][j * 256 + lane * 4] = acc[j];
    __syncthreads();

    const float mb = fmaxf(fmaxf(sm[0], sm[1]), fmaxf(sm[2], sm[3]));
    const float f0 = __expf(sm[0] - mb);
    const float f1 = __expf(sm[1] - mb);
    const float f2 = __expf(sm[2] - mb);
    const float f3 = __expf(sm[3] - mb);
    const float lb = sl[0] * f0 + sl[1] * f1 + sl[2] * f2 + sl[3] * f3;

    const int d0 = tid * 4;
    float4 a0 = *(float4*)&sacc[0][d0];
    float4 a1 = *(float4*)&sacc[1][d0];
    float4 a2 = *(float4*)&sacc[2][d0];
    float4 a3 = *(float4*)&sacc[3][d0];
    float4 o;
    o.x = a0.x * f0 + a1.x * f1 + a2.x * f2 + a3.x * f3;
    o.y = a0.y * f0 + a1.y * f1 + a2.y * f2 + a3.y * f3;
    o.z = a0.z * f0 + a1.z * f1 + a2.z * f2 + a3.z * f3;
    o.w = a0.w * f0 + a1.w * f1 + a2.w * f2 + a3.w * f3;
    *(float4*)(wc_part + ((size_t)b * NC + ch) * DD + d0) = o;

    if (tid == 0) {
        m_part[b * NC + ch] = mb;
        l_part[b * NC + ch] = lb;
    }
}

// ---------------------------------------------------------------------------
// K3: combine chunk partials -> final weighted_context, write attn output.
// grid = B, 256 threads.
// ---------------------------------------------------------------------------
__global__ __launch_bounds__(256) void combine(
    const float* __restrict__ m_part, const float* __restrict__ l_part,
    const float* __restrict__ wc_part, const float* __restrict__ scores,
    float* __restrict__ wc, float* __restrict__ attn_out)
{
    const int b = blockIdx.x;
    const int tid = threadIdx.x;

    float M = -INFINITY;
    #pragma unroll
    for (int c = 0; c < NC; ++c) M = fmaxf(M, m_part[b * NC + c]);
    float fc[NC];
    float L = 0.f;
    #pragma unroll
    for (int c = 0; c < NC; ++c) {
        fc[c] = __expf(m_part[b * NC + c] - M);
        L = fmaf(l_part[b * NC + c], fc[c], L);
    }
    const float invL = 1.f / L;

    const int d0 = tid * 4;
    float4 v = make_float4(0.f, 0.f, 0.f, 0.f);
    #pragma unroll
    for (int c = 0; c < NC; ++c) {
        float4 pv = *(const float4*)(wc_part + ((size_t)b * NC + c) * DD + d0);
        v.x = fmaf(pv.x, fc[c], v.x);
        v.y = fmaf(pv.y, fc[c], v.y);
        v.z = fmaf(pv.z, fc[c], v.z);
        v.w = fmaf(pv.w, fc[c], v.w);
    }
    v.x *= invL; v.y *= invL; v.z *= invL; v.w *= invL;
    *(float4*)(wc + (size_t)b * DD + d0) = v;

    for (int s = tid; s < SS; s += 256)
        attn_out[(size_t)b * SS + s] = __expf(scores[(size_t)b * SS + s] - M) * invL;
}

// ---------------------------------------------------------------------------
extern "C" void kernel_launch(void* const* d_in, const int* in_sizes, int n_in,
                              void* d_out, int out_size, void* d_ws, size_t ws_size,
                              hipStream_t stream)
{
    (void)in_sizes; (void)n_in; (void)out_size; (void)ws_size;

    const float* h     = (const float*)d_in[0];
    const float* ctx   = (const float*)d_in[1];
    const unsigned char* mask = (const unsigned char*)d_in[2];
    const float* W_in  = (const float*)d_in[3];
    const float* W_out = (const float*)d_in[4];

    float* out_h    = (float*)d_out;              // h_tilde [B, D]
    float* out_attn = out_h + (size_t)BB * DD;    // attn    [B, S]

    float* ws      = (float*)d_ws;
    float* target  = ws + OFF_TARGET;
    float* scores  = ws + OFF_SCORES;
    float* m_part  = ws + OFF_M;
    float* l_part  = ws + OFF_L;
    float* wc_part = ws + OFF_WCP;
    float* wc      = ws + OFF_WC;
    int*   mflag   = (int*)(ws + OFF_FLAG);

    // K0: mask dtype sniff (bool-as-byte vs int32)
    detect_mask<<<1, 64, 0, stream>>>(mask, mflag);

    // K1: target = h @ W_in^T   [128,1024]x[1024,1024]
    gemm_nt<<<dim3(32, 8), 256, 0, stream>>>(h, nullptr, W_in, target,
                                             BB, DD, 1024, 0);

    // K2: fused scores + online-softmax partials + partial weighted context
    attn_pass<<<dim3(NC, BB), 256, 0, stream>>>(ctx, target, mask, mflag,
                                                scores, m_part, l_part, wc_part);

    // K3: combine partials -> wc, attn output
    combine<<<dim3(BB), 256, 0, stream>>>(m_part, l_part, wc_part, scores,
                                          wc, out_attn);

    // K4: h_tilde = tanh(concat([wc, h]) @ W_out^T)   K=2048, tanh epilogue
    gemm_nt<<<dim3(32, 8), 256, 0, stream>>>(wc, h, W_out, out_h,
                                             BB, DD, 2048, 1);
}

// Round 6
// 735.294 us; speedup vs baseline: 1.1114x; 1.1114x over previous
//
#include <hip/hip_runtime.h>
#include <hip/hip_bf16.h>
#include <math.h>

// Problem constants (SoftDotAttention): B=128, S=1024, D=1024.
#define BB 128
#define SS 1024
#define DD 1024
#define NC 8            // S-chunks for the fused attention pass
#define SC (SS / NC)    // 128 rows per chunk
#define KSPLIT 8

// Workspace layout (floats)
#define OFF_TGT_PART 0                                  // 8*131072
#define OFF_TARGET   (OFF_TGT_PART + KSPLIT * BB * DD)  // 1048576
#define OFF_SCORES   (OFF_TARGET + BB * DD)             // +131072
#define OFF_M        (OFF_SCORES + BB * SS)
#define OFF_L        (OFF_M + BB * NC)
#define OFF_WCP      (OFF_L + BB * NC)
#define OFF_WC       (OFF_WCP + BB * NC * DD)
#define OFF_OUT_PART (OFF_WC + BB * DD)                 // 8*131072
#define OFF_FLAG     (OFF_OUT_PART + KSPLIT * BB * DD)
// total ~14.2 MB << ws_size

// ---------------------------------------------------------------------------
// K0: detect mask element width (1-byte bool vs int32 0/1). Parallel, 1 wave.
// ---------------------------------------------------------------------------
__global__ void detect_mask(const unsigned char* __restrict__ mask,
                            int* __restrict__ flag)
{
    const int tid = threadIdx.x;           // 64 threads
    int ok = 1;
    for (int i = tid; i < 256; i += 64) {
        unsigned char b0 = mask[4 * i + 0];
        unsigned char b1 = mask[4 * i + 1];
        unsigned char b2 = mask[4 * i + 2];
        unsigned char b3 = mask[4 * i + 3];
        if ((b1 | b2 | b3) != 0 || b0 > 1) ok = 0;
    }
    int all_ok = __all(ok);
    if (tid == 0) *flag = all_ok;
}

// ---------------------------------------------------------------------------
// GEMM split-K: Cpart[ks][128, N] = A[128, kchunk] * W[N, kchunk]^T
// A = A0 (k<1024) else A1 (k-1024): handles concat([wc,h]) for K4.
// 64x64 tile, 256 threads, 4x4 micro-tile, k-major transposed LDS so
// fragment reads are ds_read_b128 with only 2-way (free) bank aliasing.
// Known, deferred: staging writes are 4-way bank-conflicted (~<3% of this
// kernel) — fix only with counter evidence (pad breaks b128 alignment).
// ---------------------------------------------------------------------------
__global__ __launch_bounds__(256) void gemm_splitk(
    const float* __restrict__ A0, const float* __restrict__ A1,
    const float* __restrict__ W, float* __restrict__ Cpart,
    int N, int K)
{
    __shared__ float As_t[64][64];   // [k][row]
    __shared__ float Bs_t[64][64];   // [k][col]

    const int tid = threadIdx.x;
    const int bn0 = blockIdx.x * 64;
    const int bm0 = blockIdx.y * 64;
    const int kchunk = K / KSPLIT;
    const int kbase = blockIdx.z * kchunk;

    const int lrow = tid >> 2;          // 0..63 (staging row)
    const int lk   = (tid & 3) * 16;    // 0,16,32,48 (staging k)
    const int tr4  = (tid >> 4) * 4;    // 0..60 (compute rows)
    const int tc4  = (tid & 15) * 4;    // 0..60 (compute cols)

    float4 acc[4];
    #pragma unroll
    for (int r = 0; r < 4; ++r) acc[r] = make_float4(0.f, 0.f, 0.f, 0.f);

    for (int k0 = kbase; k0 < kbase + kchunk; k0 += 64) {
        const float* Asrc = A0;
        int kk = k0;
        if (A1 != nullptr && k0 >= 1024) { Asrc = A1; kk = k0 - 1024; }

        #pragma unroll
        for (int j = 0; j < 4; ++j) {
            float4 av = *(const float4*)(Asrc + (size_t)(bm0 + lrow) * 1024 + kk + lk + 4 * j);
            As_t[lk + 4 * j + 0][lrow] = av.x;
            As_t[lk + 4 * j + 1][lrow] = av.y;
            As_t[lk + 4 * j + 2][lrow] = av.z;
            As_t[lk + 4 * j + 3][lrow] = av.w;
            float4 wv = *(const float4*)(W + (size_t)(bn0 + lrow) * K + k0 + lk + 4 * j);
            Bs_t[lk + 4 * j + 0][lrow] = wv.x;
            Bs_t[lk + 4 * j + 1][lrow] = wv.y;
            Bs_t[lk + 4 * j + 2][lrow] = wv.z;
            Bs_t[lk + 4 * j + 3][lrow] = wv.w;
        }
        __syncthreads();

        #pragma unroll
        for (int k = 0; k < 64; ++k) {
            float4 a = *(const float4*)&As_t[k][tr4];
            float4 b = *(const float4*)&Bs_t[k][tc4];
            acc[0].x = fmaf(a.x, b.x, acc[0].x);
            acc[0].y = fmaf(a.x, b.y, acc[0].y);
            acc[0].z = fmaf(a.x, b.z, acc[0].z);
            acc[0].w = fmaf(a.x, b.w, acc[0].w);
            acc[1].x = fmaf(a.y, b.x, acc[1].x);
            acc[1].y = fmaf(a.y, b.y, acc[1].y);
            acc[1].z = fmaf(a.y, b.z, acc[1].z);
            acc[1].w = fmaf(a.y, b.w, acc[1].w);
            acc[2].x = fmaf(a.z, b.x, acc[2].x);
            acc[2].y = fmaf(a.z, b.y, acc[2].y);
            acc[2].z = fmaf(a.z, b.z, acc[2].z);
            acc[2].w = fmaf(a.z, b.w, acc[2].w);
            acc[3].x = fmaf(a.w, b.x, acc[3].x);
            acc[3].y = fmaf(a.w, b.y, acc[3].y);
            acc[3].z = fmaf(a.w, b.z, acc[3].z);
            acc[3].w = fmaf(a.w, b.w, acc[3].w);
        }
        __syncthreads();
    }

    float* base = Cpart + ((size_t)blockIdx.z * BB + bm0 + tr4) * N + bn0 + tc4;
    #pragma unroll
    for (int r = 0; r < 4; ++r)
        *(float4*)(base + (size_t)r * N) = acc[r];
}

// ---------------------------------------------------------------------------
// Reduce KSPLIT partials (float4-wide); optional tanh epilogue.
// n4 = (128*1024)/4 = 32768; grid 128 x 256.
// ---------------------------------------------------------------------------
__global__ __launch_bounds__(256) void reduce_part(
    const float* __restrict__ part, float* __restrict__ out,
    int n4, int applyTanh)
{
    const int i = blockIdx.x * 256 + threadIdx.x;
    if (i >= n4) return;
    const float4* p4 = (const float4*)part;
    float4 s = p4[i];
    #pragma unroll
    for (int ks = 1; ks < KSPLIT; ++ks) {
        float4 v = p4[(size_t)ks * n4 + i];
        s.x += v.x; s.y += v.y; s.z += v.z; s.w += v.w;
    }
    if (applyTanh) {
        s.x = tanhf(s.x); s.y = tanhf(s.y); s.z = tanhf(s.z); s.w = tanhf(s.w);
    }
    ((float4*)out)[i] = s;
}

// ---------------------------------------------------------------------------
// K2: fused scores + online softmax + partial weighted-context.
// grid = (NC, B), 256 thr = 4 waves. Wave w owns 32 consecutive rows,
// processed in groups of 4: 16 KB of loads in flight, 4 ILP'd dot/shfl
// chains, one rescale test per group (batched flash update).
// ---------------------------------------------------------------------------
__global__ __launch_bounds__(256) void attn_pass(
    const float* __restrict__ ctx, const float* __restrict__ tgt,
    const unsigned char* __restrict__ mask_u8,
    const int* __restrict__ mask_flag,
    float* __restrict__ scores, float* __restrict__ m_part,
    float* __restrict__ l_part, float* __restrict__ wc_part)
{
    const int b    = blockIdx.y;
    const int ch   = blockIdx.x;
    const int tid  = threadIdx.x;
    const int w    = tid >> 6;
    const int lane = tid & 63;
    const int sbase = ch * SC + w * 32;

    const int mflag = *mask_flag;
    const int* mask_i32 = (const int*)mask_u8;

    float4 t4[4];
    const float4* tp = (const float4*)(tgt + (size_t)b * DD);
    #pragma unroll
    for (int j = 0; j < 4; ++j) t4[j] = tp[j * 64 + lane];

    float m = -INFINITY, l = 0.f;
    float4 acc[4];
    #pragma unroll
    for (int j = 0; j < 4; ++j) acc[j] = make_float4(0.f, 0.f, 0.f, 0.f);

    float* srow = scores + (size_t)b * SS;

    for (int g = 0; g < 8; ++g) {
        const int s = sbase + g * 4;
        const float4* r0 = (const float4*)(ctx + ((size_t)b * SS + s) * DD);

        float4 c[4][4];
        #pragma unroll
        for (int rr = 0; rr < 4; ++rr)
            #pragma unroll
            for (int j = 0; j < 4; ++j)
                c[rr][j] = r0[rr * 256 + j * 64 + lane];

        float part[4];
        #pragma unroll
        for (int rr = 0; rr < 4; ++rr) {
            float p = 0.f;
            #pragma unroll
            for (int j = 0; j < 4; ++j) {
                p = fmaf(c[rr][j].x, t4[j].x, p);
                p = fmaf(c[rr][j].y, t4[j].y, p);
                p = fmaf(c[rr][j].z, t4[j].z, p);
                p = fmaf(c[rr][j].w, t4[j].w, p);
            }
            part[rr] = p;
        }
        #pragma unroll
        for (int off = 32; off >= 1; off >>= 1) {
            #pragma unroll
            for (int rr = 0; rr < 4; ++rr)
                part[rr] += __shfl_xor(part[rr], off, 64);
        }

        int mk[4];
        if (mflag) {
            int4 mi = *(const int4*)(mask_i32 + (size_t)b * SS + s);
            mk[0] = mi.x; mk[1] = mi.y; mk[2] = mi.z; mk[3] = mi.w;
        } else {
            uchar4 mu = *(const uchar4*)(mask_u8 + (size_t)b * SS + s);
            mk[0] = mu.x; mk[1] = mu.y; mk[2] = mu.z; mk[3] = mu.w;
        }
        float sc[4];
        #pragma unroll
        for (int rr = 0; rr < 4; ++rr)
            sc[rr] = mk[rr] ? -INFINITY : part[rr];

        if (lane == 0)
            *(float4*)(srow + s) = make_float4(sc[0], sc[1], sc[2], sc[3]);

        const float gm = fmaxf(fmaxf(sc[0], sc[1]), fmaxf(sc[2], sc[3]));
        if (gm > m) {                      // wave-uniform
            const float f = __expf(m - gm);
            l *= f;
            #pragma unroll
            for (int j = 0; j < 4; ++j) {
                acc[j].x *= f; acc[j].y *= f; acc[j].z *= f; acc[j].w *= f;
            }
            m = gm;
        }
        float p[4];
        #pragma unroll
        for (int rr = 0; rr < 4; ++rr)
            p[rr] = mk[rr] ? 0.f : __expf(sc[rr] - m);
        l += (p[0] + p[1]) + (p[2] + p[3]);

        #pragma unroll
        for (int j = 0; j < 4; ++j) {
            float4 a = acc[j];
            #pragma unroll
            for (int rr = 0; rr < 4; ++rr) {
                a.x = fmaf(p[rr], c[rr][j].x, a.x);
                a.y = fmaf(p[rr], c[rr][j].y, a.y);
                a.z = fmaf(p[rr], c[rr][j].z, a.z);
                a.w = fmaf(p[rr], c[rr][j].w, a.w);
            }
            acc[j] = a;
        }
    }

    // ---- combine the 4 waves ----
    __shared__ float sm[4], sl[4];
    __shared__ float sacc[4][DD];
    if (lane == 0) { sm[w] = m; sl[w] = l; }
    #pragma unroll
    for (int j = 0; j < 4; ++j)
        *(float4*)&sacc[w][j * 256 + lane * 4] = acc[j];
    __syncthreads();

    const float mb = fmaxf(fmaxf(sm[0], sm[1]), fmaxf(sm[2], sm[3]));
    const float f0 = __expf(sm[0] - mb);
    const float f1 = __expf(sm[1] - mb);
    const float f2 = __expf(sm[2] - mb);
    const float f3 = __expf(sm[3] - mb);
    const float lb = sl[0] * f0 + sl[1] * f1 + sl[2] * f2 + sl[3] * f3;

    const int d0 = tid * 4;
    float4 a0 = *(float4*)&sacc[0][d0];
    float4 a1 = *(float4*)&sacc[1][d0];
    float4 a2 = *(float4*)&sacc[2][d0];
    float4 a3 = *(float4*)&sacc[3][d0];
    float4 o;
    o.x = a0.x * f0 + a1.x * f1 + a2.x * f2 + a3.x * f3;
    o.y = a0.y * f0 + a1.y * f1 + a2.y * f2 + a3.y * f3;
    o.z = a0.z * f0 + a1.z * f1 + a2.z * f2 + a3.z * f3;
    o.w = a0.w * f0 + a1.w * f1 + a2.w * f2 + a3.w * f3;
    *(float4*)(wc_part + ((size_t)b * NC + ch) * DD + d0) = o;

    if (tid == 0) {
        m_part[b * NC + ch] = mb;
        l_part[b * NC + ch] = lb;
    }
}

// ---------------------------------------------------------------------------
// K3: combine chunk partials -> final weighted_context + attn output.
// ---------------------------------------------------------------------------
__global__ __launch_bounds__(256) void combine(
    const float* __restrict__ m_part, const float* __restrict__ l_part,
    const float* __restrict__ wc_part, const float* __restrict__ scores,
    float* __restrict__ wc, float* __restrict__ attn_out)
{
    const int b = blockIdx.x;
    const int tid = threadIdx.x;

    float M = -INFINITY;
    #pragma unroll
    for (int c = 0; c < NC; ++c) M = fmaxf(M, m_part[b * NC + c]);
    float fc[NC];
    float L = 0.f;
    #pragma unroll
    for (int c = 0; c < NC; ++c) {
        fc[c] = __expf(m_part[b * NC + c] - M);
        L = fmaf(l_part[b * NC + c], fc[c], L);
    }
    const float invL = 1.f / L;

    const int d0 = tid * 4;
    float4 v = make_float4(0.f, 0.f, 0.f, 0.f);
    #pragma unroll
    for (int c = 0; c < NC; ++c) {
        float4 pv = *(const float4*)(wc_part + ((size_t)b * NC + c) * DD + d0);
        v.x = fmaf(pv.x, fc[c], v.x);
        v.y = fmaf(pv.y, fc[c], v.y);
        v.z = fmaf(pv.z, fc[c], v.z);
        v.w = fmaf(pv.w, fc[c], v.w);
    }
    v.x *= invL; v.y *= invL; v.z *= invL; v.w *= invL;
    *(float4*)(wc + (size_t)b * DD + d0) = v;

    for (int s = tid; s < SS; s += 256)
        attn_out[(size_t)b * SS + s] = __expf(scores[(size_t)b * SS + s] - M) * invL;
}

// ---------------------------------------------------------------------------
extern "C" void kernel_launch(void* const* d_in, const int* in_sizes, int n_in,
                              void* d_out, int out_size, void* d_ws, size_t ws_size,
                              hipStream_t stream)
{
    (void)in_sizes; (void)n_in; (void)out_size; (void)ws_size;

    const float* h     = (const float*)d_in[0];
    const float* ctx   = (const float*)d_in[1];
    const unsigned char* mask = (const unsigned char*)d_in[2];
    const float* W_in  = (const float*)d_in[3];
    const float* W_out = (const float*)d_in[4];

    float* out_h    = (float*)d_out;              // h_tilde [B, D]
    float* out_attn = out_h + (size_t)BB * DD;    // attn    [B, S]

    float* ws       = (float*)d_ws;
    float* tgt_part = ws + OFF_TGT_PART;
    float* target   = ws + OFF_TARGET;
    float* scores   = ws + OFF_SCORES;
    float* m_part   = ws + OFF_M;
    float* l_part   = ws + OFF_L;
    float* wc_part  = ws + OFF_WCP;
    float* wc       = ws + OFF_WC;
    float* out_part = ws + OFF_OUT_PART;
    int*   mflag    = (int*)(ws + OFF_FLAG);

    // K0: mask dtype sniff
    detect_mask<<<1, 64, 0, stream>>>(mask, mflag);

    // K1: target partials = h @ W_in^T (split-K), then reduce
    gemm_splitk<<<dim3(16, 2, KSPLIT), 256, 0, stream>>>(h, nullptr, W_in,
                                                         tgt_part, DD, 1024);
    reduce_part<<<dim3(128), 256, 0, stream>>>(tgt_part, target, BB * DD / 4, 0);

    // K2: fused scores + online-softmax partials + partial weighted context
    attn_pass<<<dim3(NC, BB), 256, 0, stream>>>(ctx, target, mask, mflag,
                                                scores, m_part, l_part, wc_part);

    // K3: combine partials -> wc, attn output
    combine<<<dim3(BB), 256, 0, stream>>>(m_part, l_part, wc_part, scores,
                                          wc, out_attn);

    // K4: h_tilde partials = concat([wc,h]) @ W_out^T (split-K), reduce+tanh
    gemm_splitk<<<dim3(16, 2, KSPLIT), 256, 0, stream>>>(wc, h, W_out,
                                                         out_part, DD, 2048);
    reduce_part<<<dim3(128), 256, 0, stream>>>(out_part, out_h, BB * DD / 4, 1);
}